// Round 9
// baseline (2639.505 us; speedup 1.0000x reference)
//
#include <hip/hip_runtime.h>
#include <stdint.h>

typedef unsigned int u32;
typedef unsigned short u16;
typedef unsigned long long u64;

#define L_VERTS 65536
#define N_EDGES 130560
#define N_NODES 131071   // 2*L - 1
#define NODEPAD 131072

// chunked-parallel tree build: after MST filter only 65535 edges remain.
// All MST-stream edges merge -> node id of sorted MST rank p is L_VERTS+p
// (R6-validated), so p2 writes usize16/intra-chunk parents directly and p3
// keeps only the cross-chunk stitch.
#define CCH 170          // allocation sizing (kept from full-edge version)
#define CCHM 86          // active chunks: 86*768 = 66048 >= 65535
#define SCH 768
#define PADM (CCHM*SCH)  // 66048
#define NMST (L_VERTS-1) // 65535 MST edges (connected grid)
#define MAXSV 1536
#define HSZ 2048

// ---------------- radix sort (stable LSD, index ping-pong, gathered keys) ----
#define NB 255
#define TPB 64
#define IPT 8
#define IPB 512

__global__ void init_keys(const float* __restrict__ w, u32* __restrict__ keys, u32* __restrict__ vals,
                          u32* szG, u16* canonTop16, u32* parent, float* alt){
  int i = blockIdx.x*blockDim.x + threadIdx.x;
  if(i < N_EDGES){ keys[i] = __float_as_uint(w[i]); vals[i] = (u32)i; } // w>=0 -> uint order == float order
  if(i < N_NODES){ parent[i]=(u32)i; alt[i]=0.f; }
  if(i < L_VERTS){ szG[i]=1u; canonTop16[i]=0xFFFFu; }
}

__global__ void radix_hist(const u32* __restrict__ idx, const u32* __restrict__ keys,
                           u32* __restrict__ histG, int shift){
  __shared__ u32 h[256];
  for(int i=threadIdx.x;i<256;i+=TPB) h[i]=0;
  __syncthreads();
  int base = blockIdx.x*IPB + threadIdx.x*IPT;
  #pragma unroll
  for(int i=0;i<IPT;i++){
    u32 e = idx[base+i];
    u32 d = (keys[e]>>shift)&255u;
    atomicAdd(&h[d],1u);
  }
  __syncthreads();
  for(int i=threadIdx.x;i<256;i+=TPB) histG[i*NB+blockIdx.x]=h[i];  // digit-major
}

__global__ void radix_scan(u32* histG){
  const int M = 256*NB;
  __shared__ u32 sums[1024];
  int t=threadIdx.x; int s=t*64; u32 acc=0;
  for(int i=0;i<64;i++){int id=s+i; if(id<M) acc+=histG[id];}
  sums[t]=acc; __syncthreads();
  for(int off=1; off<1024; off<<=1){
    u32 v=(t>=off)?sums[t-off]:0u;
    __syncthreads();
    sums[t]+=v;
    __syncthreads();
  }
  u32 run = (t==0)?0u:sums[t-1];
  for(int i=0;i<64;i++){int id=s+i; if(id<M){u32 v=histG[id]; histG[id]=run; run+=v;}}
}

__global__ void radix_scatter(const u32* __restrict__ idxIn, const u32* __restrict__ keys,
                              u32* __restrict__ idxOut, const u32* __restrict__ histG, int shift){
  __shared__ u16 thoff[256][TPB];
  int t=threadIdx.x;
  for(int d=t;d<256;d+=TPB) for(int j=0;j<TPB;j++) thoff[d][j]=0;
  __syncthreads();
  int base = blockIdx.x*IPB + t*IPT;
  u32 myv[IPT]; u32 myd[IPT];
  #pragma unroll
  for(int i=0;i<IPT;i++){
    myv[i]=idxIn[base+i];
    myd[i]=(keys[myv[i]]>>shift)&255u;
    thoff[myd[i]][t]++;
  }
  __syncthreads();
  for(int dd=0;dd<4;dd++){
    int d=t*4+dd; u32 run=0;
    for(int j=0;j<TPB;j++){ u32 v=thoff[d][j]; thoff[d][j]=(u16)run; run+=v; }
  }
  __syncthreads();
  #pragma unroll
  for(int i=0;i<IPT;i++){
    u32 d=myd[i];
    u32 pos = histG[d*NB+blockIdx.x] + (u32)thoff[d][t];
    thoff[d][t]++;                       // stable within thread
    idxOut[pos]=myv[i];
  }
}

// epair[p] = (dst<<16)|src for sorted position p
__global__ void build_epair(const u32* __restrict__ order, const int* __restrict__ srcv,
                            const int* __restrict__ dstv, u32* __restrict__ epair){
  int p=blockIdx.x*blockDim.x+threadIdx.x;
  if(p>=N_EDGES) return;
  u32 e=order[p];
  epair[p]=((u32)dstv[e]<<16)|(u32)srcv[e];
}

// ---------------- Borůvka MST filter (multi-dispatch, R2/R5-proven) ----------
// Stream-ordered dead-round guard (R6-validated). R9: 3 dispatches/round —
// minE ping-pong lets hookB also reset the NEXT round's minE buffer (nobody
// reads it this round) and run a best-effort compress (hooks only from
// verified roots with stable-buffer mutual tie-break keep the forest acyclic;
// compression writes only point at ancestors, so concurrent walks stay valid).
#define CBK 255
#define CT 512
#define DEADE 0xFFFFFFFFu

__device__ __forceinline__ u32 bfind(const u32* __restrict__ parentB, u32 x){
  while(true){ u32 p=parentB[x]; if(p==x) return x; x=p; }
}

__global__ void bor_init(u32* parentB, u32* minEa, u32* minEb, unsigned char* mstF, u32* bctr){
  int i=blockIdx.x*blockDim.x+threadIdx.x;
  if(i<L_VERTS){ parentB[i]=(u32)i; minEa[i]=0xFFFFFFFFu; minEb[i]=0xFFFFFFFFu; }
  if(i<N_EDGES) mstF[i]=0;
  if(i<16) bctr[i]=0u;
}

__global__ void bor_minedge(u32* __restrict__ epair, const u32* __restrict__ parentB,
                            u32* __restrict__ minE, const unsigned char* __restrict__ mstF,
                            const u32* __restrict__ bctr, int r){
  if(r>0 && bctr[r-1]==0u) return;
  int p=blockIdx.x*blockDim.x+threadIdx.x;   // grid covers N_EDGES exactly
  u32 pr=epair[p];
  if(pr==DEADE) return;
  u32 ra=bfind(parentB, pr&0xFFFFu), rb=bfind(parentB, pr>>16);
  if(ra==rb){ if(!mstF[p]) epair[p]=DEADE; return; }   // keep MST pairs for scatter
  atomicMin(&minE[ra],(u32)p);
  atomicMin(&minE[rb],(u32)p);
}

// hookA: roots compute partner root + mark MST edge (reads only; no parentB writes)
__global__ void bor_hookA(const u32* __restrict__ epair, const u32* __restrict__ parentB,
                          const u32* __restrict__ minE, u32* __restrict__ nextB,
                          unsigned char* __restrict__ mstF, const u32* __restrict__ bctr, int r){
  if(r>0 && bctr[r-1]==0u) return;
  int v=blockIdx.x*blockDim.x+threadIdx.x;
  if(v>=L_VERTS) return;
  if(parentB[v]!=(u32)v) return;
  u32 p=minE[v];
  if(p==0xFFFFFFFFu) return;
  u32 pr=epair[p];
  u32 ra=bfind(parentB, pr&0xFFFFu), rb=bfind(parentB, pr>>16);
  u32 w2=(ra==(u32)v)?rb:ra;
  nextB[v]=w2;
  mstF[p]=1;                                   // mutual pair: both write 1 (benign)
}

// hookB: apply hooks (reads ONLY the stable cur-minE/nextB) + reset NEXT
// round's minE + best-effort compress.
__global__ void bor_hookB(u32* __restrict__ parentB, const u32* __restrict__ minEcur,
                          u32* __restrict__ minEnext, const u32* __restrict__ nextB,
                          u32* __restrict__ bctr, int r){
  if(r>0 && bctr[r-1]==0u) return;
  int v=blockIdx.x*blockDim.x+threadIdx.x;
  if(v>=L_VERTS) return;
  if(parentB[v]==(u32)v){
    u32 p=minEcur[v];
    if(p!=0xFFFFFFFFu){
      u32 w2=nextB[v];
      if(!(minEcur[w2]==p && (u32)v<w2)){      // star center stays root
        parentB[v]=w2;
        bctr[r]=1u;                            // benign same-value race
      }
    }
  }
  minEnext[v]=0xFFFFFFFFu;
  // best-effort compress (valid under concurrent root-hooks)
  u32 x=(u32)v;
  while(true){ u32 px=parentB[x]; if(px==x) break; u32 g=parentB[px]; if(g!=px) parentB[x]=g; x=g; }
  parentB[v]=x;
}

// ---- stable compaction of MST edges in sorted order (255 blocks x 512) ------
__global__ void mst_count(const unsigned char* __restrict__ mstF, u32* __restrict__ blockCnt){
  int b=blockIdx.x, t=threadIdx.x;
  int p=b*CT+t;
  u64 m=__ballot(mstF[p]!=0);
  __shared__ u32 ws[8];
  if((t&63)==0) ws[t>>6]=(u32)__popcll(m);
  __syncthreads();
  if(t==0){ u32 s=0; for(int i=0;i<8;i++) s+=ws[i]; blockCnt[b]=s; }
}

__global__ void mst_scan(const u32* __restrict__ blockCnt, u32* __restrict__ blockBase,
                         u32* __restrict__ mepair){
  int t=threadIdx.x;                    // 256 threads
  __shared__ u32 s[256];
  u32 v=(t<CBK)?blockCnt[t]:0u;
  s[t]=v; __syncthreads();
  for(int o=1;o<256;o<<=1){ u32 x=(t>=o)?s[t-o]:0u; __syncthreads(); s[t]+=x; __syncthreads(); }
  if(t<CBK) blockBase[t]=s[t]-v;        // exclusive base
  u32 total=s[255];                     // pad from MEASURED total (robust)
  for(u32 j=total+(u32)t; j<(u32)PADM; j+=256u) mepair[j]=0u;  // self-edge (0,0)
}

// writes alt[L_VERTS+rank] directly (node id = L + sorted MST rank; R6-validated)
__global__ void mst_scatter(const unsigned char* __restrict__ mstF, const u32* __restrict__ blockBase,
                            const u32* __restrict__ order, const u32* __restrict__ epair,
                            const float* __restrict__ w,
                            u32* __restrict__ mepair, float* __restrict__ alt){
  int b=blockIdx.x, t=threadIdx.x;
  int p=b*CT+t;
  u32 f=(u32)mstF[p];
  u64 m=__ballot(f!=0);
  __shared__ u32 ws[8];
  int wid=t>>6, lane=t&63;
  if(lane==0) ws[wid]=(u32)__popcll(m);
  __syncthreads();
  if(t==0){ u32 s2=0; for(int i=0;i<8;i++){ u32 x=ws[i]; ws[i]=s2; s2+=x; } }
  __syncthreads();
  if(f){
    u32 pre=(u32)__popcll(m & ((1ull<<lane)-1ull));
    u32 pos=blockBase[b]+ws[wid]+pre;
    mepair[pos]=epair[p];
    alt[(u32)L_VERTS+pos]=w[order[p]];
  }
}

__device__ __forceinline__ u32 ald(u32* p){
  return __hip_atomic_load(p, __ATOMIC_RELAXED, __HIP_MEMORY_SCOPE_AGENT);
}

// ---------------- P1: checkpoints + global CC (1 block x 1024) ---------------
// R9: compsz/phase5 removed — phase4 adds member sizes straight into
// szG[wv] via global atomics (szG[wv] already holds wv's own size, so the
// total is exact). 4 barriers/chunk. LDS ~152 KB.
__global__ void __launch_bounds__(1024,1) p1_checkpoints(
    const u32* __restrict__ epair,
    u32* szG, u16* lid16, u16* svroot16, u16* svsize16, u16* svnext16, u32* mG)
{
  __shared__ u16 ufL[L_VERTS];     // 128 KB
  __shared__ u32 hkey[HSZ];        // 8 KB  ((root<<16)|id)
  __shared__ u32 sufL[MAXSV];      // 6 KB  (id-space UF)
  __shared__ u16 ssz[MAXSV];       // 3 KB  (per-id size-1 stash)
  __shared__ u16 svtx[MAXSV];      // 3 KB  (per-id root vertex)
  __shared__ u16 lidL[2*SCH];      // 3 KB  (item -> hash slot)
  __shared__ u32 mcnt;
  int t = threadIdx.x;
  for(int i=t;i<L_VERTS/2;i+=1024) ((u32*)ufL)[i]=((2u*(u32)i+1u)<<16)|(2u*(u32)i); // ufL[v]=v
  for(int k=0;k<CCHM;k++){
    // phase0: init hash + slot arrays
    for(int i=t;i<HSZ;i+=1024) hkey[i]=0xFFFFFFFFu;
    for(u32 s=t;s<MAXSV;s+=1024) sufL[s]=s;
    if(t==0) mcnt=0u;
    __syncthreads();
    int base = k*SCH;
    // phase1: find + claim (flat strided); slot staged to lidL
    for(int i=t;i<2*SCH;i+=1024){
      u32 pr = epair[base+(i>>1)];
      u32 v = (i&1)? (pr>>16) : (pr&0xFFFFu);
      u32 x=v;
      while(true){ u32 px=ufL[x]; if(px==x)break; u32 g=ufL[px]; if(g!=px) ufL[x]=(u16)g; x=g; }
      u32 r=x;
      if(v!=r) ufL[v]=(u16)r;       // direct compression (benign race; no hooks this phase)
      u32 h=(r*2654435761u)>>21;    // [0,2048)
      while(true){
        u32 old=atomicCAS(&hkey[h],0xFFFFFFFFu,(r<<16)|0x7FFFu);
        if(old==0xFFFFFFFFu){
          u32 id=atomicAdd(&mcnt,1u);
          svroot16[k*MAXSV+id]=(u16)r;
          svtx[id]=(u16)r;
          hkey[h]=(r<<16)|id;       // low-bits fixup; probes compare >>16 only
          break;
        }
        if((old>>16)==r) break;
        h=(h+1)&(HSZ-1u);
      }
      lidL[i]=(u16)h;
    }
    __syncthreads();
    // phase2+3: szG gather (parallel; root vertex from LDS svtx) + lid
    // emission + id-space unions
    u32 mc=mcnt;
    if(t==0) mG[k]=mc;
    for(u32 s=t;s<mc;s+=1024){
      u32 r=(u32)svtx[s];
      u32 szm1=ald(&szG[r])-1u;
      svsize16[k*MAXSV+s]=(u16)szm1;
      ssz[s]=(u16)szm1;
    }
    for(int i=t;i<2*SCH;i+=1024) lid16[2*base+i]=(u16)(hkey[lidL[i]]&0xFFFFu);
    for(int j=t;j<SCH;j+=1024){
      u32 sa=hkey[lidL[2*j]]&0xFFFFu, sb=hkey[lidL[2*j+1]]&0xFFFFu;
      if(sa==sb) continue;
      while(true){
        u32 x=sa; while(true){u32 p2=sufL[x]; if(p2==x)break; u32 g=sufL[p2]; if(g!=p2) sufL[x]=g; x=g;}
        u32 y=sb; while(true){u32 p2=sufL[y]; if(p2==y)break; u32 g=sufL[p2]; if(g!=p2) sufL[y]=g; y=g;}
        if(x==y) break;
        u32 hi=x>y?x:y, lo=x^y^hi;
        if(atomicCAS(&sufL[hi],hi,lo)==hi) break;
        sa=hi; sb=lo;
      }
    }
    __syncthreads();
    // phase4: find root + outputs + star hooks + direct szG accumulation
    for(u32 s=t;s<mc;s+=1024){
      u32 x=s; while(true){u32 p2=sufL[x]; if(p2==x)break; x=p2;}
      sufL[s]=x;                                  // values only decrease -> safe
      u32 wv=(u32)svtx[x];                        // rep = root id's vertex
      svnext16[k*MAXSV+s]=(u16)wv;
      u32 myroot=(u32)svtx[s];
      if(myroot!=wv){
        ufL[myroot]=(u16)wv;                      // star hook, one writer per root
        atomicAdd(&szG[wv], (u32)ssz[s]+1u);      // fold member size into rep
      }
    }
    __syncthreads();
  }
}

// ---------------- P2: per-chunk local Kruskal (CCHM blocks) ------------------
// Static node ids (R6-validated) — every non-pad edge merges, so merge
// index == j and nid = L + k*SCH + j. p2 writes usize16 + intra-chunk
// parent links directly.
__global__ void __launch_bounds__(64) p2_chunk(
  const u16* __restrict__ lid16,
  const u16* __restrict__ svsize16, const u16* __restrict__ svnext16, const u32* __restrict__ mG,
  u16* __restrict__ outChA, u16* __restrict__ outChB,
  u32* __restrict__ parent, u16* __restrict__ usize16,
  u16* __restrict__ compR16, u16* __restrict__ compTop16, u32* __restrict__ ncomp)
{
  int k = blockIdx.x; int t = threadIdx.x;
  __shared__ u16 uf[MAXSV];
  __shared__ u32 csize[MAXSV];
  __shared__ u16 ctop[MAXSV];
  __shared__ u16 svnl[MAXSV];
  __shared__ u32 lidP[SCH];        // preloaded lid pairs -> serial loop is pure-LDS
  __shared__ u32 cmp_s;
  u32 m = mG[k];
  int base=k*SCH;
  for(u32 s=t;s<m;s+=64){
    uf[s]=(u16)s;
    csize[s]=(u32)svsize16[k*MAXSV+s]+1u;
    ctop[s]=(u16)s;
    svnl[s]=svnext16[k*MAXSV+s];
  }
  for(int j=t;j<SCH;j+=64) lidP[j]=((const u32*)lid16)[base+j];
  if(t==0) cmp_s=0u;
  __syncthreads();
  int nk=(k==CCHM-1)?(NMST-(CCHM-1)*SCH):SCH;
  if(t==0){
    for(int j=0;j<nk;j++){
      u32 lw = lidP[j];
      u32 la = lw & 0xFFFFu, lb = lw >> 16;
      u32 x=la; while(true){u32 px=uf[x]; if(px==x)break; u32 g=uf[px]; uf[x]=(u16)g; x=g;}
      u32 y=lb; while(true){u32 py=uf[y]; if(py==y)break; u32 g=uf[py]; uf[y]=(u16)g; y=g;}
      if(x==y) continue;               // cannot happen on MST stream (defensive)
      u32 sa=csize[x], sb=csize[y], ns=sa+sb;
      u32 nid=(u32)L_VERTS+(u32)base+(u32)j;
      u32 cA=ctop[x], cB=ctop[y];
      if(cA&0x8000u) parent[(u32)L_VERTS+(u32)base+(cA&0x7FFFu)]=nid;
      if(cB&0x8000u) parent[(u32)L_VERTS+(u32)base+(cB&0x7FFFu)]=nid;
      outChA[base+j]=(u16)cA;
      outChB[base+j]=(u16)cB;
      usize16[nid]=(u16)(ns-1u);
      u32 win=(sa>=sb)?x:y, los=x^y^win;
      uf[los]=(u16)win; csize[win]=ns; ctop[win]=(u16)(0x8000u|(u32)j);
    }
  }
  __syncthreads();
  for(u32 s=t;s<m;s+=64){
    if(uf[s]==(u16)s && (ctop[s]&0x8000u)){
      u32 pos=atomicAdd(&cmp_s,1u);
      compR16[k*MAXSV+pos]=svnl[s];
      compTop16[k*MAXSV+pos]=(u16)(ctop[s]&0x7FFFu);
    }
  }
  __syncthreads();
  if(t==0) ncomp[k]=cmp_s;
}

// ---------------- P3: stitch cross-chunk children (1 block x 1024) -----------
__global__ void __launch_bounds__(1024) p3_stitch(
  const u16* __restrict__ outChA, const u16* __restrict__ outChB,
  const u16* __restrict__ svroot16,
  const u16* __restrict__ compR16, const u16* __restrict__ compTop16, const u32* __restrict__ ncomp,
  u16* __restrict__ canonTop16, u32* __restrict__ parent)
{
  int t=threadIdx.x;
  for(int k=0;k<CCHM;k++){
    int base=k*SCH;
    int nk=(k==CCHM-1)?(NMST-(CCHM-1)*SCH):SCH;
    for(int j=t;j<nk;j+=1024){
      int idx=base+j;
      u32 nid=(u32)L_VERTS+(u32)idx;
      u32 cA=outChA[idx];
      if(!(cA&0x8000u)){
        u32 root=(u32)svroot16[k*MAXSV+cA];
        u32 ct=(u32)canonTop16[root];
        parent[(ct==0xFFFFu)?root:((u32)L_VERTS+ct)]=nid;
      }
      u32 cB=outChB[idx];
      if(!(cB&0x8000u)){
        u32 root=(u32)svroot16[k*MAXSV+cB];
        u32 ct=(u32)canonTop16[root];
        parent[(ct==0xFFFFu)?root:((u32)L_VERTS+ct)]=nid;
      }
    }
    __syncthreads();
    u32 nc=ncomp[k];
    for(u32 j=t;j<nc;j+=1024){
      canonTop16[(u32)compR16[k*MAXSV+j]] = (u16)((u32)base + (u32)compTop16[k*MAXSV+j]);
    }
    __syncthreads();
  }
}

// ---------------- softarea via degree-5 sigmoid poly + DFS intervals ---------
__device__ __forceinline__ void hvals6(float v, float* o){
  float v2=v*v, v3=v2*v, v4=v2*v2, v5=v4*v;
  o[0]=0.5f-0.25f*v+v3*(1.f/48.f)-v5*(1.f/480.f);
  o[1]=0.25f-v2*(1.f/16.f)+v4*(1.f/96.f);
  o[2]=v*(1.f/16.f)-v3*(1.f/48.f);
  o[3]=v2*(1.f/48.f)-(1.f/48.f);
  o[4]=-v*(1.f/96.f);
  o[5]=(1.f/480.f);
}

__global__ void zero_cc(u32* cc, u32* ctr){
  int i=blockIdx.x*blockDim.x+threadIdx.x;
  if(i<L_VERTS) cc[i]=0u;
  if(i==0) *ctr=0u;
}

// also zeroes nodeM (6 rows, coalesced)
__global__ void prep_init(const u32* __restrict__ parent, const u16* __restrict__ usize16,
                          u32* cc, u32* J0, uint2* A0, float* out, float* __restrict__ nodeM){
  int n=blockIdx.x*blockDim.x+threadIdx.x;
  if(n<NODEPAD){
    #pragma unroll
    for(int j=0;j<6;j++) nodeM[(size_t)j*NODEPAD+n]=0.f;
  }
  if(n>=N_NODES) return;
  out[n] = (n<L_VERTS)?0.5f:0.0f;
  if(n==N_NODES-1){ J0[n]=(u32)n; A0[n]=make_uint2(0u,0u); return; }  // root
  u32 p=parent[n];
  u32 ord=atomicAdd(&cc[p-L_VERTS],1u);          // 0 or 1: child order
  u32 szP=(u32)usize16[p]+1u;
  u32 szN=(n<L_VERTS)?1u:((u32)usize16[n]+1u);
  u32 sib=szP-szN;
  A0[n]=make_uint2(ord? sib:0u, 1u + (ord? (2u*sib-1u):0u));
  J0[n]=p;
}

__global__ void triple_round(const u32* __restrict__ Jin, const uint2* __restrict__ Ain,
                             u32* __restrict__ Jout, uint2* __restrict__ Aout){
  int n=blockIdx.x*blockDim.x+threadIdx.x;
  if(n>=N_NODES) return;
  u32 j1=Jin[n], j2=Jin[j1], j3=Jin[j2], j4=Jin[j3], j5=Jin[j4], j6=Jin[j5], j7=Jin[j6];
  uint2 a0=Ain[n], a1=Ain[j1], a2=Ain[j2], a3=Ain[j3], a4=Ain[j4], a5=Ain[j5], a6=Ain[j6], a7=Ain[j7];
  Aout[n]=make_uint2(a0.x+a1.x+a2.x+a3.x+a4.x+a5.x+a6.x+a7.x,
                     a0.y+a1.y+a2.y+a3.y+a4.y+a5.y+a6.y+a7.y);
  Jout[n]=Jin[j7];
}

__global__ void scatter_all(const u32* __restrict__ parent, const float* __restrict__ alt,
                            const u16* __restrict__ usize16, const uint2* __restrict__ accF,
                            float* __restrict__ leafM, float* __restrict__ nodeM){
  int n=blockIdx.x*blockDim.x+threadIdx.x;
  if(n>=N_NODES) return;
  u32 p=parent[n];
  float h[6]; hvals6(alt[p],h);
  uint2 af=accF[n];
  if(n<L_VERTS){
    u32 pos=af.x;
    #pragma unroll
    for(int j=0;j<6;j++) leafM[(size_t)j*L_VERTS+pos]=h[j];
  }
  if(n<N_NODES-1){
    u32 szP=(u32)usize16[p]+1u;
    u32 szN=(n<L_VERTS)?1u:((u32)usize16[n]+1u);
    float d=(float)(szP-szN);
    u32 q0=af.y;
    u32 q1=q0 + 2u*szN - 1u;
    #pragma unroll
    for(int j=0;j<6;j++){
      float tm=d*h[j];
      atomicAdd(&nodeM[(size_t)j*NODEPAD+q0], tm);
      atomicAdd(&nodeM[(size_t)j*NODEPAD+q1], -tm);
    }
  }
}

__global__ void scanAll(float* __restrict__ leafM, float* __restrict__ nodeM,
                        float* __restrict__ bsumL, float* __restrict__ bsumN, u32* ctr){
  int b=blockIdx.x; int t=threadIdx.x;
  float* arr; u32 base; float* bs;
  if(b<6*64){ int row=b>>6, blk=b&63;  arr=leafM+(size_t)row*L_VERTS;  base=(u32)blk*1024u; bs=&bsumL[row*64+blk]; }
  else      { int bb=b-384; int row=bb>>7, blk=bb&127; arr=nodeM+(size_t)row*NODEPAD; base=(u32)blk*1024u; bs=&bsumN[row*128+blk]; }
  __shared__ float s[256];
  __shared__ u32 lastFlag;
  base += (u32)t*4u;
  float v0=arr[base],v1=arr[base+1],v2=arr[base+2],v3=arr[base+3];
  v1+=v0; v2+=v1; v3+=v2;
  s[t]=v3; __syncthreads();
  for(int o=1;o<256;o<<=1){ float x=(t>=o)?s[t-o]:0.f; __syncthreads(); s[t]+=x; __syncthreads(); }
  float pre=(t>0)?s[t-1]:0.f;
  arr[base]=v0+pre; arr[base+1]=v1+pre; arr[base+2]=v2+pre; arr[base+3]=v3+pre;
  if(t==255) *bs=s[255];
  __threadfence();
  if(t==0) lastFlag = (atomicAdd(ctr,1u)==1151u) ? 1u : 0u;
  __syncthreads();
  if(lastFlag){
    __threadfence();
    if(t<6){ float r=0; for(int i=0;i<64;i++){ float v=bsumL[t*64+i]; bsumL[t*64+i]=r; r+=v; } }
    else if(t<12){ int j=t-6; float r=0; for(int i=0;i<128;i++){ float v=bsumN[j*128+i]; bsumN[j*128+i]=r; r+=v; } }
  }
}

__global__ void eval_all(const uint2* __restrict__ accF, const float* __restrict__ alt,
                         const u16* __restrict__ usize16, const float* __restrict__ leafM,
                         const float* __restrict__ nodeM, const float* __restrict__ bsumL,
                         const float* __restrict__ bsumN, float* __restrict__ out){
  int n=blockIdx.x*blockDim.x+threadIdx.x;
  if(n>=N_NODES) return;
  uint2 af=accF[n];
  float u=alt[n];
  u32 q=af.y;
  float acc=0.f, up=1.f;
  #pragma unroll
  for(int j=0;j<6;j++){
    float T = nodeM[(size_t)j*NODEPAD+q] + bsumN[j*128 + (q>>10)];
    acc += up*T;
    up*=u;
  }
  if(n>=L_VERTS){
    u32 lo=af.x;
    u32 hi=lo + (u32)usize16[n] + 1u;
    up=1.f;
    #pragma unroll
    for(int j=0;j<6;j++){
      const float* arr=leafM + (size_t)j*L_VERTS;
      const float* bs=bsumL + j*64;
      float Ph = arr[hi-1u] + bs[(hi-1u)>>10];
      float Pl = lo ? (arr[lo-1u] + bs[(lo-1u)>>10]) : 0.f;
      acc += up*(Ph-Pl);
      up*=u;
    }
  }
  out[n]+=acc;
}

__global__ void ws_too_small(float* out){
  int i=blockIdx.x*blockDim.x+threadIdx.x;
  if(i<N_NODES) out[i]=1.0e6f;
}

// ---------------- launch ----------------
extern "C" void kernel_launch(void* const* d_in, const int* in_sizes, int n_in,
                              void* d_out, int out_size, void* d_ws, size_t ws_size,
                              hipStream_t stream){
  (void)in_sizes; (void)n_in; (void)out_size;
  const float* w  = (const float*)d_in[0];
  const int* src  = (const int*)d_in[1];
  const int* dst  = (const int*)d_in[2];
  float* out = (float*)d_out;

  char* ws = (char*)d_ws;
  size_t off=0;
  auto alloc=[&](size_t bytes)->void*{ void* p = ws+off; off += (bytes+511)&~(size_t)511; return p; };
  // persistent
  u32* parent   =(u32*)alloc((size_t)N_NODES*4);
  float* alt    =(float*)alloc((size_t)N_NODES*4);
  u16* usize16  =(u16*)alloc((size_t)N_NODES*2);
  float* bsumL  =(float*)alloc(6*64*4);
  float* bsumN  =(float*)alloc(6*128*4);
  u32* ctr      =(u32*)alloc(512);
  size_t scratch0=off;
  // phase A (sort + build) — dead after p3
  u32* keys0    =(u32*)alloc((size_t)N_EDGES*4); // after sort: epair; in p2: outChB16
  u32* vals0    =(u32*)alloc((size_t)N_EDGES*4); // sorted order (alive through compaction)
  u32* vals1    =(u32*)alloc((size_t)N_EDGES*4); // sort scratch -> lid16
  u32* histG    =(u32*)alloc(256*NB*4);          // dead after sort -> outChA16
  u16* canonTop16=(u16*)alloc((size_t)L_VERTS*2);
  u16* svroot16 =(u16*)alloc((size_t)CCH*MAXSV*2);
  u16* svsize16 =(u16*)alloc((size_t)CCH*MAXSV*2); // dead after P2 load -> compR16
  u16* svnext16 =(u16*)alloc((size_t)CCH*MAXSV*2); // dead after P2 load -> compTop16
  u32* mG       =(u32*)alloc(CCH*4);
  u32* ncomp    =(u32*)alloc(CCH*4);
  // Borůvka MST filter scratch — dead before phase B's nodeM overlay is written.
  u32* parentB  =(u32*)alloc((size_t)L_VERTS*4);
  u32* minEa    =(u32*)alloc((size_t)L_VERTS*4);
  u32* minEb    =(u32*)alloc((size_t)L_VERTS*4);
  u32* nextB    =(u32*)alloc((size_t)L_VERTS*4);
  unsigned char* mstF=(unsigned char*)alloc((size_t)N_EDGES);
  u32* blockCnt =(u32*)alloc(256*4);
  u32* blockBase=(u32*)alloc(256*4);
  u32* mepair   =(u32*)alloc((size_t)PADM*4);    // compacted (dst<<16)|src, tail padded 0
  u32* bctr     =(u32*)alloc(512);               // per-round hooked flags
  size_t endA=off;
  // phase B (poly softarea) — overlays phase A scratch
  off=scratch0;
  u32* ccChsum  =(u32*)alloc((size_t)L_VERTS*4);     // childCnt for prep_init
  u32* J0       =(u32*)alloc((size_t)N_NODES*4);
  u32* J1       =(u32*)alloc((size_t)N_NODES*4);
  uint2* A0     =(uint2*)alloc((size_t)N_NODES*8);
  uint2* A1     =(uint2*)alloc((size_t)N_NODES*8);   // survives: accF after 6 launches
  float* nodeM  =(float*)alloc((size_t)6*NODEPAD*4);
  size_t endB=off;
  float* leafM  =(float*)ccChsum;

  if((endA>ws_size)||(endB>ws_size)){
    ws_too_small<<<(N_NODES+255)/256,256,0,stream>>>(out);
    return;
  }

  u16* lid16    =(u16*)vals1;
  u32* epair    =keys0;                          // keys dead after sort
  u16* outChA16 =(u16*)histG;
  u16* outChB16 =(u16*)keys0;                    // written by p2 (after Borůvka done with epair)
  u16* compR16  =svsize16;
  u16* compTop16=svnext16;
  u32* szG      =(u32*)usize16;                  // u32[L_VERTS] aliases usize16; dead after p1

  // --- sort (+ fused tree-array init) ---
  init_keys<<<(N_NODES+255)/256,256,0,stream>>>(w,keys0,vals0,szG,canonTop16,parent,alt);
  for(int pass=0;pass<4;pass++){
    const u32* iv = (pass&1)?vals1:vals0;
    u32* ov = (pass&1)?vals0:vals1;
    int shift=pass*8;
    radix_hist   <<<NB,TPB,0,stream>>>(iv,keys0,histG,shift);
    radix_scan   <<<1,1024,0,stream>>>(histG);
    radix_scatter<<<NB,TPB,0,stream>>>(iv,keys0,ov,histG,shift);
  }
  build_epair<<<(N_EDGES+255)/256,256,0,stream>>>(vals0,src,dst,epair);
  // --- Borůvka MST filter on sorted ranks (unique keys == stable Kruskal) ---
  bor_init<<<CBK,CT,0,stream>>>(parentB,minEa,minEb,mstF,bctr);
  for(int r=0;r<16;r++){   // dead rounds early-return via stream-ordered flag
    u32* mcur=(r&1)?minEb:minEa;
    u32* mnxt=(r&1)?minEa:minEb;
    bor_minedge <<<CBK,CT,0,stream>>>(epair,parentB,mcur,mstF,bctr,r);
    bor_hookA   <<<L_VERTS/CT,CT,0,stream>>>(epair,parentB,mcur,nextB,mstF,bctr,r);
    bor_hookB   <<<L_VERTS/CT,CT,0,stream>>>(parentB,mcur,mnxt,nextB,bctr,r);
  }
  mst_count  <<<CBK,CT,0,stream>>>(mstF,blockCnt);
  mst_scan   <<<1,256,0,stream>>>(blockCnt,blockBase,mepair);
  mst_scatter<<<CBK,CT,0,stream>>>(mstF,blockBase,vals0,epair,w,mepair,alt);
  // --- tree build on 65535-edge compacted stream (86 chunks) ---
  p1_checkpoints<<<1,1024,0,stream>>>(mepair,szG,lid16,svroot16,svsize16,svnext16,mG);
  p2_chunk<<<CCHM,64,0,stream>>>(lid16,svsize16,svnext16,mG,outChA16,outChB16,
                                 parent,usize16,compR16,compTop16,ncomp);
  p3_stitch<<<1,1024,0,stream>>>(outChA16,outChB16,svroot16,
                                 compR16,compTop16,ncomp,canonTop16,parent);
  // --- DFS coordinates via fused pointer doubling (6 launches x 3 rounds) ---
  zero_cc<<<(L_VERTS+255)/256,256,0,stream>>>(ccChsum,ctr);
  prep_init<<<(NODEPAD+255)/256,256,0,stream>>>(parent,usize16,ccChsum,J1,A1,out,nodeM);
  for(int r=0;r<6;r++){
    if((r&1)==0) triple_round<<<(N_NODES+255)/256,256,0,stream>>>(J1,A1,J0,A0);
    else         triple_round<<<(N_NODES+255)/256,256,0,stream>>>(J0,A0,J1,A1);
  }
  const uint2* accF=A1;
  // --- single merged moment batch (all 6 h-rows) ---
  scatter_all<<<(N_NODES+255)/256,256,0,stream>>>(parent,alt,usize16,accF,leafM,nodeM);
  scanAll<<<1152,256,0,stream>>>(leafM,nodeM,bsumL,bsumN,ctr);
  eval_all<<<(N_NODES+255)/256,256,0,stream>>>(accF,alt,usize16,leafM,nodeM,bsumL,bsumN,out);
}

// Round 10
// 2581.832 us; speedup vs baseline: 1.0223x; 1.0223x over previous
//
#include <hip/hip_runtime.h>
#include <stdint.h>

typedef unsigned int u32;
typedef unsigned short u16;
typedef unsigned long long u64;

#define L_VERTS 65536
#define N_EDGES 130560
#define N_NODES 131071   // 2*L - 1
#define NODEPAD 131072

// chunked-parallel tree build: after MST filter only 65535 edges remain.
// All MST-stream edges merge -> node id of sorted MST rank p is L_VERTS+p
// (R6-validated), so p2 writes usize16/intra-chunk parents directly and p3
// keeps only the cross-chunk stitch.
#define CCH 170          // allocation sizing (kept from full-edge version)
#define CCHM 86          // active chunks: 86*768 = 66048 >= 65535
#define SCH 768
#define PADM (CCHM*SCH)  // 66048
#define NMST (L_VERTS-1) // 65535 MST edges (connected grid)
#define MAXSV 1536
#define HSZ 2048

// ---------------- radix sort (stable LSD, index ping-pong, gathered keys) ----
#define NB 255
#define TPB 64
#define IPT 8
#define IPB 512

__global__ void init_keys(const float* __restrict__ w, u32* __restrict__ keys, u32* __restrict__ vals,
                          u32* szG, u16* canonTop16, u32* parent, float* alt){
  int i = blockIdx.x*blockDim.x + threadIdx.x;
  if(i < N_EDGES){ keys[i] = __float_as_uint(w[i]); vals[i] = (u32)i; } // w>=0 -> uint order == float order
  if(i < N_NODES){ parent[i]=(u32)i; alt[i]=0.f; }
  if(i < L_VERTS){ szG[i]=1u; canonTop16[i]=0xFFFFu; }
}

__global__ void radix_hist(const u32* __restrict__ idx, const u32* __restrict__ keys,
                           u32* __restrict__ histG, int shift){
  __shared__ u32 h[256];
  for(int i=threadIdx.x;i<256;i+=TPB) h[i]=0;
  __syncthreads();
  int base = blockIdx.x*IPB + threadIdx.x*IPT;
  #pragma unroll
  for(int i=0;i<IPT;i++){
    u32 e = idx[base+i];
    u32 d = (keys[e]>>shift)&255u;
    atomicAdd(&h[d],1u);
  }
  __syncthreads();
  for(int i=threadIdx.x;i<256;i+=TPB) histG[i*NB+blockIdx.x]=h[i];  // digit-major
}

__global__ void radix_scan(u32* histG){
  const int M = 256*NB;
  __shared__ u32 sums[1024];
  int t=threadIdx.x; int s=t*64; u32 acc=0;
  for(int i=0;i<64;i++){int id=s+i; if(id<M) acc+=histG[id];}
  sums[t]=acc; __syncthreads();
  for(int off=1; off<1024; off<<=1){
    u32 v=(t>=off)?sums[t-off]:0u;
    __syncthreads();
    sums[t]+=v;
    __syncthreads();
  }
  u32 run = (t==0)?0u:sums[t-1];
  for(int i=0;i<64;i++){int id=s+i; if(id<M){u32 v=histG[id]; histG[id]=run; run+=v;}}
}

__global__ void radix_scatter(const u32* __restrict__ idxIn, const u32* __restrict__ keys,
                              u32* __restrict__ idxOut, const u32* __restrict__ histG, int shift){
  __shared__ u16 thoff[256][TPB];
  int t=threadIdx.x;
  for(int d=t;d<256;d+=TPB) for(int j=0;j<TPB;j++) thoff[d][j]=0;
  __syncthreads();
  int base = blockIdx.x*IPB + t*IPT;
  u32 myv[IPT]; u32 myd[IPT];
  #pragma unroll
  for(int i=0;i<IPT;i++){
    myv[i]=idxIn[base+i];
    myd[i]=(keys[myv[i]]>>shift)&255u;
    thoff[myd[i]][t]++;
  }
  __syncthreads();
  for(int dd=0;dd<4;dd++){
    int d=t*4+dd; u32 run=0;
    for(int j=0;j<TPB;j++){ u32 v=thoff[d][j]; thoff[d][j]=(u16)run; run+=v; }
  }
  __syncthreads();
  #pragma unroll
  for(int i=0;i<IPT;i++){
    u32 d=myd[i];
    u32 pos = histG[d*NB+blockIdx.x] + (u32)thoff[d][t];
    thoff[d][t]++;                       // stable within thread
    idxOut[pos]=myv[i];
  }
}

// epair[p] = (dst<<16)|src for sorted position p
__global__ void build_epair(const u32* __restrict__ order, const int* __restrict__ srcv,
                            const int* __restrict__ dstv, u32* __restrict__ epair){
  int p=blockIdx.x*blockDim.x+threadIdx.x;
  if(p>=N_EDGES) return;
  u32 e=order[p];
  epair[p]=((u32)dstv[e]<<16)|(u32)srcv[e];
}

// ---------------- Borůvka MST filter (3 dispatches/round, R9-validated) ------
// Stream-ordered dead-round guard (R6-validated). minE ping-pong lets hookB
// also reset the NEXT round's minE buffer (nobody reads it this round) and
// run a best-effort compress (hooks only from verified roots with
// stable-buffer mutual tie-break keep the forest acyclic; compression writes
// only point at ancestors, so concurrent walks stay valid).
#define CBK 255
#define CT 512
#define DEADE 0xFFFFFFFFu

__device__ __forceinline__ u32 bfind(const u32* __restrict__ parentB, u32 x){
  while(true){ u32 p=parentB[x]; if(p==x) return x; x=p; }
}

__global__ void bor_init(u32* parentB, u32* minEa, u32* minEb, unsigned char* mstF, u32* bctr){
  int i=blockIdx.x*blockDim.x+threadIdx.x;
  if(i<L_VERTS){ parentB[i]=(u32)i; minEa[i]=0xFFFFFFFFu; minEb[i]=0xFFFFFFFFu; }
  if(i<N_EDGES) mstF[i]=0;
  if(i<16) bctr[i]=0u;
}

__global__ void bor_minedge(u32* __restrict__ epair, const u32* __restrict__ parentB,
                            u32* __restrict__ minE, const unsigned char* __restrict__ mstF,
                            const u32* __restrict__ bctr, int r){
  if(r>0 && bctr[r-1]==0u) return;
  int p=blockIdx.x*blockDim.x+threadIdx.x;   // grid covers N_EDGES exactly
  u32 pr=epair[p];
  if(pr==DEADE) return;
  u32 ra=bfind(parentB, pr&0xFFFFu), rb=bfind(parentB, pr>>16);
  if(ra==rb){ if(!mstF[p]) epair[p]=DEADE; return; }   // keep MST pairs for scatter
  atomicMin(&minE[ra],(u32)p);
  atomicMin(&minE[rb],(u32)p);
}

// hookA: roots compute partner root + mark MST edge (reads only; no parentB writes)
__global__ void bor_hookA(const u32* __restrict__ epair, const u32* __restrict__ parentB,
                          const u32* __restrict__ minE, u32* __restrict__ nextB,
                          unsigned char* __restrict__ mstF, const u32* __restrict__ bctr, int r){
  if(r>0 && bctr[r-1]==0u) return;
  int v=blockIdx.x*blockDim.x+threadIdx.x;
  if(v>=L_VERTS) return;
  if(parentB[v]!=(u32)v) return;
  u32 p=minE[v];
  if(p==0xFFFFFFFFu) return;
  u32 pr=epair[p];
  u32 ra=bfind(parentB, pr&0xFFFFu), rb=bfind(parentB, pr>>16);
  u32 w2=(ra==(u32)v)?rb:ra;
  nextB[v]=w2;
  mstF[p]=1;                                   // mutual pair: both write 1 (benign)
}

// hookB: apply hooks (reads ONLY the stable cur-minE/nextB) + reset NEXT
// round's minE + best-effort compress.
__global__ void bor_hookB(u32* __restrict__ parentB, const u32* __restrict__ minEcur,
                          u32* __restrict__ minEnext, const u32* __restrict__ nextB,
                          u32* __restrict__ bctr, int r){
  if(r>0 && bctr[r-1]==0u) return;
  int v=blockIdx.x*blockDim.x+threadIdx.x;
  if(v>=L_VERTS) return;
  if(parentB[v]==(u32)v){
    u32 p=minEcur[v];
    if(p!=0xFFFFFFFFu){
      u32 w2=nextB[v];
      if(!(minEcur[w2]==p && (u32)v<w2)){      // star center stays root
        parentB[v]=w2;
        bctr[r]=1u;                            // benign same-value race
      }
    }
  }
  minEnext[v]=0xFFFFFFFFu;
  // best-effort compress (valid under concurrent root-hooks)
  u32 x=(u32)v;
  while(true){ u32 px=parentB[x]; if(px==x) break; u32 g=parentB[px]; if(g!=px) parentB[x]=g; x=g; }
  parentB[v]=x;
}

// ---- stable compaction of MST edges in sorted order (255 blocks x 512) ------
__global__ void mst_count(const unsigned char* __restrict__ mstF, u32* __restrict__ blockCnt){
  int b=blockIdx.x, t=threadIdx.x;
  int p=b*CT+t;
  u64 m=__ballot(mstF[p]!=0);
  __shared__ u32 ws[8];
  if((t&63)==0) ws[t>>6]=(u32)__popcll(m);
  __syncthreads();
  if(t==0){ u32 s=0; for(int i=0;i<8;i++) s+=ws[i]; blockCnt[b]=s; }
}

__global__ void mst_scan(const u32* __restrict__ blockCnt, u32* __restrict__ blockBase,
                         u32* __restrict__ mepair){
  int t=threadIdx.x;                    // 256 threads
  __shared__ u32 s[256];
  u32 v=(t<CBK)?blockCnt[t]:0u;
  s[t]=v; __syncthreads();
  for(int o=1;o<256;o<<=1){ u32 x=(t>=o)?s[t-o]:0u; __syncthreads(); s[t]+=x; __syncthreads(); }
  if(t<CBK) blockBase[t]=s[t]-v;        // exclusive base
  u32 total=s[255];                     // pad from MEASURED total (robust)
  for(u32 j=total+(u32)t; j<(u32)PADM; j+=256u) mepair[j]=0u;  // self-edge (0,0)
}

// writes alt[L_VERTS+rank] directly (node id = L + sorted MST rank; R6-validated)
__global__ void mst_scatter(const unsigned char* __restrict__ mstF, const u32* __restrict__ blockBase,
                            const u32* __restrict__ order, const u32* __restrict__ epair,
                            const float* __restrict__ w,
                            u32* __restrict__ mepair, float* __restrict__ alt){
  int b=blockIdx.x, t=threadIdx.x;
  int p=b*CT+t;
  u32 f=(u32)mstF[p];
  u64 m=__ballot(f!=0);
  __shared__ u32 ws[8];
  int wid=t>>6, lane=t&63;
  if(lane==0) ws[wid]=(u32)__popcll(m);
  __syncthreads();
  if(t==0){ u32 s2=0; for(int i=0;i<8;i++){ u32 x=ws[i]; ws[i]=s2; s2+=x; } }
  __syncthreads();
  if(f){
    u32 pre=(u32)__popcll(m & ((1ull<<lane)-1ull));
    u32 pos=blockBase[b]+ws[wid]+pre;
    mepair[pos]=epair[p];
    alt[(u32)L_VERTS+pos]=w[order[p]];
  }
}

__device__ __forceinline__ u32 ald(u32* p){
  return __hip_atomic_load(p, __ATOMIC_RELAXED, __HIP_MEMORY_SCOPE_AGENT);
}
__device__ __forceinline__ void ast(u32* p, u32 v){
  __hip_atomic_store(p, v, __ATOMIC_RELAXED, __HIP_MEMORY_SCOPE_AGENT);
}

// ---------------- P1: checkpoints + global CC (1 block x 1024) ---------------
// R8-proven form (best measured: 1095 us): LDS svtx root-vertex cache,
// LDS compsz aggregation in phase4' (fused with outputs/star-hooks),
// phase5' = one szG store per component. R9's szG-direct atomics REVERTED
// (global-atomic latency on the serial path cost +65 us).
__global__ void __launch_bounds__(1024,1) p1_checkpoints(
    const u32* __restrict__ epair,
    u32* szG, u16* lid16, u16* svroot16, u16* svsize16, u16* svnext16, u32* mG)
{
  __shared__ u16 ufL[L_VERTS];     // 128 KB
  __shared__ u32 hkey[HSZ];        // 8 KB  ((root<<16)|id)
  __shared__ u32 sufL[MAXSV];      // 6 KB  (id-space UF)
  __shared__ u32 compsz[MAXSV];    // 6 KB
  __shared__ u16 ssz[MAXSV];       // 3 KB  (per-id size-1 stash)
  __shared__ u16 svtx[MAXSV];      // 3 KB  (per-id root vertex)
  __shared__ u16 lidL[2*SCH];      // 3 KB  (item -> hash slot)
  __shared__ u32 mcnt;
  int t = threadIdx.x;
  for(int i=t;i<L_VERTS/2;i+=1024) ((u32*)ufL)[i]=((2u*(u32)i+1u)<<16)|(2u*(u32)i); // ufL[v]=v
  for(int k=0;k<CCHM;k++){
    // phase0: init hash + slot arrays
    for(int i=t;i<HSZ;i+=1024) hkey[i]=0xFFFFFFFFu;
    for(u32 s=t;s<MAXSV;s+=1024){ sufL[s]=s; compsz[s]=0u; }
    if(t==0) mcnt=0u;
    __syncthreads();
    int base = k*SCH;
    // phase1: find + claim (flat strided); slot staged to lidL
    for(int i=t;i<2*SCH;i+=1024){
      u32 pr = epair[base+(i>>1)];
      u32 v = (i&1)? (pr>>16) : (pr&0xFFFFu);
      u32 x=v;
      while(true){ u32 px=ufL[x]; if(px==x)break; u32 g=ufL[px]; if(g!=px) ufL[x]=(u16)g; x=g; }
      u32 r=x;
      if(v!=r) ufL[v]=(u16)r;       // direct compression (benign race; no hooks this phase)
      u32 h=(r*2654435761u)>>21;    // [0,2048)
      while(true){
        u32 old=atomicCAS(&hkey[h],0xFFFFFFFFu,(r<<16)|0x7FFFu);
        if(old==0xFFFFFFFFu){
          u32 id=atomicAdd(&mcnt,1u);
          svroot16[k*MAXSV+id]=(u16)r;
          svtx[id]=(u16)r;
          hkey[h]=(r<<16)|id;       // low-bits fixup; probes compare >>16 only
          break;
        }
        if((old>>16)==r) break;
        h=(h+1)&(HSZ-1u);
      }
      lidL[i]=(u16)h;
    }
    __syncthreads();
    // phase2+3: szG gather (parallel; root vertex from LDS svtx) + lid
    // emission + id-space unions
    u32 mc=mcnt;
    if(t==0) mG[k]=mc;
    for(u32 s=t;s<mc;s+=1024){
      u32 r=(u32)svtx[s];
      u32 szm1=ald(&szG[r])-1u;
      svsize16[k*MAXSV+s]=(u16)szm1;
      ssz[s]=(u16)szm1;
    }
    for(int i=t;i<2*SCH;i+=1024) lid16[2*base+i]=(u16)(hkey[lidL[i]]&0xFFFFu);
    for(int j=t;j<SCH;j+=1024){
      u32 sa=hkey[lidL[2*j]]&0xFFFFu, sb=hkey[lidL[2*j+1]]&0xFFFFu;
      if(sa==sb) continue;
      while(true){
        u32 x=sa; while(true){u32 p2=sufL[x]; if(p2==x)break; u32 g=sufL[p2]; if(g!=p2) sufL[x]=g; x=g;}
        u32 y=sb; while(true){u32 p2=sufL[y]; if(p2==y)break; u32 g=sufL[p2]; if(g!=p2) sufL[y]=g; y=g;}
        if(x==y) break;
        u32 hi=x>y?x:y, lo=x^y^hi;
        if(atomicCAS(&sufL[hi],hi,lo)==hi) break;
        sa=hi; sb=lo;
      }
    }
    __syncthreads();
    // phase4': find root + size aggregation + outputs + star hooks (fused)
    for(u32 s=t;s<mc;s+=1024){
      u32 x=s; while(true){u32 p2=sufL[x]; if(p2==x)break; x=p2;}
      sufL[s]=x;                                  // values only decrease -> safe
      atomicAdd(&compsz[x], (u32)ssz[s]+1u);
      u32 wv=(u32)svtx[x];                        // rep = root id's vertex
      svnext16[k*MAXSV+s]=(u16)wv;
      u32 myroot=(u32)svtx[s];
      if(myroot!=wv) ufL[myroot]=(u16)wv;         // star hook, one writer per root
    }
    __syncthreads();
    // phase5': per-component szG store (needs completed compsz)
    for(u32 s=t;s<mc;s+=1024){
      if(sufL[s]==s) ast(&szG[(u32)svtx[s]], compsz[s]);
    }
    __syncthreads();
  }
}

// ---------------- P2: per-chunk local Kruskal (CCHM blocks) ------------------
// Static node ids (R6-validated) — every non-pad edge merges, so merge
// index == j and nid = L + k*SCH + j. p2 writes usize16 + intra-chunk
// parent links directly.
__global__ void __launch_bounds__(64) p2_chunk(
  const u16* __restrict__ lid16,
  const u16* __restrict__ svsize16, const u16* __restrict__ svnext16, const u32* __restrict__ mG,
  u16* __restrict__ outChA, u16* __restrict__ outChB,
  u32* __restrict__ parent, u16* __restrict__ usize16,
  u16* __restrict__ compR16, u16* __restrict__ compTop16, u32* __restrict__ ncomp)
{
  int k = blockIdx.x; int t = threadIdx.x;
  __shared__ u16 uf[MAXSV];
  __shared__ u32 csize[MAXSV];
  __shared__ u16 ctop[MAXSV];
  __shared__ u16 svnl[MAXSV];
  __shared__ u32 lidP[SCH];        // preloaded lid pairs -> serial loop is pure-LDS
  __shared__ u32 cmp_s;
  u32 m = mG[k];
  int base=k*SCH;
  for(u32 s=t;s<m;s+=64){
    uf[s]=(u16)s;
    csize[s]=(u32)svsize16[k*MAXSV+s]+1u;
    ctop[s]=(u16)s;
    svnl[s]=svnext16[k*MAXSV+s];
  }
  for(int j=t;j<SCH;j+=64) lidP[j]=((const u32*)lid16)[base+j];
  if(t==0) cmp_s=0u;
  __syncthreads();
  int nk=(k==CCHM-1)?(NMST-(CCHM-1)*SCH):SCH;
  if(t==0){
    for(int j=0;j<nk;j++){
      u32 lw = lidP[j];
      u32 la = lw & 0xFFFFu, lb = lw >> 16;
      u32 x=la; while(true){u32 px=uf[x]; if(px==x)break; u32 g=uf[px]; uf[x]=(u16)g; x=g;}
      u32 y=lb; while(true){u32 py=uf[y]; if(py==y)break; u32 g=uf[py]; uf[y]=(u16)g; y=g;}
      if(x==y) continue;               // cannot happen on MST stream (defensive)
      u32 sa=csize[x], sb=csize[y], ns=sa+sb;
      u32 nid=(u32)L_VERTS+(u32)base+(u32)j;
      u32 cA=ctop[x], cB=ctop[y];
      if(cA&0x8000u) parent[(u32)L_VERTS+(u32)base+(cA&0x7FFFu)]=nid;
      if(cB&0x8000u) parent[(u32)L_VERTS+(u32)base+(cB&0x7FFFu)]=nid;
      outChA[base+j]=(u16)cA;
      outChB[base+j]=(u16)cB;
      usize16[nid]=(u16)(ns-1u);
      u32 win=(sa>=sb)?x:y, los=x^y^win;
      uf[los]=(u16)win; csize[win]=ns; ctop[win]=(u16)(0x8000u|(u32)j);
    }
  }
  __syncthreads();
  for(u32 s=t;s<m;s+=64){
    if(uf[s]==(u16)s && (ctop[s]&0x8000u)){
      u32 pos=atomicAdd(&cmp_s,1u);
      compR16[k*MAXSV+pos]=svnl[s];
      compTop16[k*MAXSV+pos]=(u16)(ctop[s]&0x7FFFu);
    }
  }
  __syncthreads();
  if(t==0) ncomp[k]=cmp_s;
}

// ---------------- P3: stitch cross-chunk children (1 block x 1024) -----------
__global__ void __launch_bounds__(1024) p3_stitch(
  const u16* __restrict__ outChA, const u16* __restrict__ outChB,
  const u16* __restrict__ svroot16,
  const u16* __restrict__ compR16, const u16* __restrict__ compTop16, const u32* __restrict__ ncomp,
  u16* __restrict__ canonTop16, u32* __restrict__ parent)
{
  int t=threadIdx.x;
  for(int k=0;k<CCHM;k++){
    int base=k*SCH;
    int nk=(k==CCHM-1)?(NMST-(CCHM-1)*SCH):SCH;
    for(int j=t;j<nk;j+=1024){
      int idx=base+j;
      u32 nid=(u32)L_VERTS+(u32)idx;
      u32 cA=outChA[idx];
      if(!(cA&0x8000u)){
        u32 root=(u32)svroot16[k*MAXSV+cA];
        u32 ct=(u32)canonTop16[root];
        parent[(ct==0xFFFFu)?root:((u32)L_VERTS+ct)]=nid;
      }
      u32 cB=outChB[idx];
      if(!(cB&0x8000u)){
        u32 root=(u32)svroot16[k*MAXSV+cB];
        u32 ct=(u32)canonTop16[root];
        parent[(ct==0xFFFFu)?root:((u32)L_VERTS+ct)]=nid;
      }
    }
    __syncthreads();
    u32 nc=ncomp[k];
    for(u32 j=t;j<nc;j+=1024){
      canonTop16[(u32)compR16[k*MAXSV+j]] = (u16)((u32)base + (u32)compTop16[k*MAXSV+j]);
    }
    __syncthreads();
  }
}

// ---------------- softarea via degree-5 sigmoid poly + DFS intervals ---------
__device__ __forceinline__ void hvals6(float v, float* o){
  float v2=v*v, v3=v2*v, v4=v2*v2, v5=v4*v;
  o[0]=0.5f-0.25f*v+v3*(1.f/48.f)-v5*(1.f/480.f);
  o[1]=0.25f-v2*(1.f/16.f)+v4*(1.f/96.f);
  o[2]=v*(1.f/16.f)-v3*(1.f/48.f);
  o[3]=v2*(1.f/48.f)-(1.f/48.f);
  o[4]=-v*(1.f/96.f);
  o[5]=(1.f/480.f);
}

__global__ void zero_cc(u32* cc, u32* ctr){
  int i=blockIdx.x*blockDim.x+threadIdx.x;
  if(i<L_VERTS) cc[i]=0u;
  if(i==0) *ctr=0u;
}

// also zeroes nodeM (6 rows, coalesced)
__global__ void prep_init(const u32* __restrict__ parent, const u16* __restrict__ usize16,
                          u32* cc, u32* J0, uint2* A0, float* out, float* __restrict__ nodeM){
  int n=blockIdx.x*blockDim.x+threadIdx.x;
  if(n<NODEPAD){
    #pragma unroll
    for(int j=0;j<6;j++) nodeM[(size_t)j*NODEPAD+n]=0.f;
  }
  if(n>=N_NODES) return;
  out[n] = (n<L_VERTS)?0.5f:0.0f;
  if(n==N_NODES-1){ J0[n]=(u32)n; A0[n]=make_uint2(0u,0u); return; }  // root
  u32 p=parent[n];
  u32 ord=atomicAdd(&cc[p-L_VERTS],1u);          // 0 or 1: child order
  u32 szP=(u32)usize16[p]+1u;
  u32 szN=(n<L_VERTS)?1u:((u32)usize16[n]+1u);
  u32 sib=szP-szN;
  A0[n]=make_uint2(ord? sib:0u, 1u + (ord? (2u*sib-1u):0u));
  J0[n]=p;
}

__global__ void triple_round(const u32* __restrict__ Jin, const uint2* __restrict__ Ain,
                             u32* __restrict__ Jout, uint2* __restrict__ Aout){
  int n=blockIdx.x*blockDim.x+threadIdx.x;
  if(n>=N_NODES) return;
  u32 j1=Jin[n], j2=Jin[j1], j3=Jin[j2], j4=Jin[j3], j5=Jin[j4], j6=Jin[j5], j7=Jin[j6];
  uint2 a0=Ain[n], a1=Ain[j1], a2=Ain[j2], a3=Ain[j3], a4=Ain[j4], a5=Ain[j5], a6=Ain[j6], a7=Ain[j7];
  Aout[n]=make_uint2(a0.x+a1.x+a2.x+a3.x+a4.x+a5.x+a6.x+a7.x,
                     a0.y+a1.y+a2.y+a3.y+a4.y+a5.y+a6.y+a7.y);
  Jout[n]=Jin[j7];
}

__global__ void scatter_all(const u32* __restrict__ parent, const float* __restrict__ alt,
                            const u16* __restrict__ usize16, const uint2* __restrict__ accF,
                            float* __restrict__ leafM, float* __restrict__ nodeM){
  int n=blockIdx.x*blockDim.x+threadIdx.x;
  if(n>=N_NODES) return;
  u32 p=parent[n];
  float h[6]; hvals6(alt[p],h);
  uint2 af=accF[n];
  if(n<L_VERTS){
    u32 pos=af.x;
    #pragma unroll
    for(int j=0;j<6;j++) leafM[(size_t)j*L_VERTS+pos]=h[j];
  }
  if(n<N_NODES-1){
    u32 szP=(u32)usize16[p]+1u;
    u32 szN=(n<L_VERTS)?1u:((u32)usize16[n]+1u);
    float d=(float)(szP-szN);
    u32 q0=af.y;
    u32 q1=q0 + 2u*szN - 1u;
    #pragma unroll
    for(int j=0;j<6;j++){
      float tm=d*h[j];
      atomicAdd(&nodeM[(size_t)j*NODEPAD+q0], tm);
      atomicAdd(&nodeM[(size_t)j*NODEPAD+q1], -tm);
    }
  }
}

__global__ void scanAll(float* __restrict__ leafM, float* __restrict__ nodeM,
                        float* __restrict__ bsumL, float* __restrict__ bsumN, u32* ctr){
  int b=blockIdx.x; int t=threadIdx.x;
  float* arr; u32 base; float* bs;
  if(b<6*64){ int row=b>>6, blk=b&63;  arr=leafM+(size_t)row*L_VERTS;  base=(u32)blk*1024u; bs=&bsumL[row*64+blk]; }
  else      { int bb=b-384; int row=bb>>7, blk=bb&127; arr=nodeM+(size_t)row*NODEPAD; base=(u32)blk*1024u; bs=&bsumN[row*128+blk]; }
  __shared__ float s[256];
  __shared__ u32 lastFlag;
  base += (u32)t*4u;
  float v0=arr[base],v1=arr[base+1],v2=arr[base+2],v3=arr[base+3];
  v1+=v0; v2+=v1; v3+=v2;
  s[t]=v3; __syncthreads();
  for(int o=1;o<256;o<<=1){ float x=(t>=o)?s[t-o]:0.f; __syncthreads(); s[t]+=x; __syncthreads(); }
  float pre=(t>0)?s[t-1]:0.f;
  arr[base]=v0+pre; arr[base+1]=v1+pre; arr[base+2]=v2+pre; arr[base+3]=v3+pre;
  if(t==255) *bs=s[255];
  __threadfence();
  if(t==0) lastFlag = (atomicAdd(ctr,1u)==1151u) ? 1u : 0u;
  __syncthreads();
  if(lastFlag){
    __threadfence();
    if(t<6){ float r=0; for(int i=0;i<64;i++){ float v=bsumL[t*64+i]; bsumL[t*64+i]=r; r+=v; } }
    else if(t<12){ int j=t-6; float r=0; for(int i=0;i<128;i++){ float v=bsumN[j*128+i]; bsumN[j*128+i]=r; r+=v; } }
  }
}

__global__ void eval_all(const uint2* __restrict__ accF, const float* __restrict__ alt,
                         const u16* __restrict__ usize16, const float* __restrict__ leafM,
                         const float* __restrict__ nodeM, const float* __restrict__ bsumL,
                         const float* __restrict__ bsumN, float* __restrict__ out){
  int n=blockIdx.x*blockDim.x+threadIdx.x;
  if(n>=N_NODES) return;
  uint2 af=accF[n];
  float u=alt[n];
  u32 q=af.y;
  float acc=0.f, up=1.f;
  #pragma unroll
  for(int j=0;j<6;j++){
    float T = nodeM[(size_t)j*NODEPAD+q] + bsumN[j*128 + (q>>10)];
    acc += up*T;
    up*=u;
  }
  if(n>=L_VERTS){
    u32 lo=af.x;
    u32 hi=lo + (u32)usize16[n] + 1u;
    up=1.f;
    #pragma unroll
    for(int j=0;j<6;j++){
      const float* arr=leafM + (size_t)j*L_VERTS;
      const float* bs=bsumL + j*64;
      float Ph = arr[hi-1u] + bs[(hi-1u)>>10];
      float Pl = lo ? (arr[lo-1u] + bs[(lo-1u)>>10]) : 0.f;
      acc += up*(Ph-Pl);
      up*=u;
    }
  }
  out[n]+=acc;
}

__global__ void ws_too_small(float* out){
  int i=blockIdx.x*blockDim.x+threadIdx.x;
  if(i<N_NODES) out[i]=1.0e6f;
}

// ---------------- launch ----------------
extern "C" void kernel_launch(void* const* d_in, const int* in_sizes, int n_in,
                              void* d_out, int out_size, void* d_ws, size_t ws_size,
                              hipStream_t stream){
  (void)in_sizes; (void)n_in; (void)out_size;
  const float* w  = (const float*)d_in[0];
  const int* src  = (const int*)d_in[1];
  const int* dst  = (const int*)d_in[2];
  float* out = (float*)d_out;

  char* ws = (char*)d_ws;
  size_t off=0;
  auto alloc=[&](size_t bytes)->void*{ void* p = ws+off; off += (bytes+511)&~(size_t)511; return p; };
  // persistent
  u32* parent   =(u32*)alloc((size_t)N_NODES*4);
  float* alt    =(float*)alloc((size_t)N_NODES*4);
  u16* usize16  =(u16*)alloc((size_t)N_NODES*2);
  float* bsumL  =(float*)alloc(6*64*4);
  float* bsumN  =(float*)alloc(6*128*4);
  u32* ctr      =(u32*)alloc(512);
  size_t scratch0=off;
  // phase A (sort + build) — dead after p3
  u32* keys0    =(u32*)alloc((size_t)N_EDGES*4); // after sort: epair; in p2: outChB16
  u32* vals0    =(u32*)alloc((size_t)N_EDGES*4); // sorted order (alive through compaction)
  u32* vals1    =(u32*)alloc((size_t)N_EDGES*4); // sort scratch -> lid16
  u32* histG    =(u32*)alloc(256*NB*4);          // dead after sort -> outChA16
  u16* canonTop16=(u16*)alloc((size_t)L_VERTS*2);
  u16* svroot16 =(u16*)alloc((size_t)CCH*MAXSV*2);
  u16* svsize16 =(u16*)alloc((size_t)CCH*MAXSV*2); // dead after P2 load -> compR16
  u16* svnext16 =(u16*)alloc((size_t)CCH*MAXSV*2); // dead after P2 load -> compTop16
  u32* mG       =(u32*)alloc(CCH*4);
  u32* ncomp    =(u32*)alloc(CCH*4);
  // Borůvka MST filter scratch — dead before phase B's nodeM overlay is written.
  u32* parentB  =(u32*)alloc((size_t)L_VERTS*4);
  u32* minEa    =(u32*)alloc((size_t)L_VERTS*4);
  u32* minEb    =(u32*)alloc((size_t)L_VERTS*4);
  u32* nextB    =(u32*)alloc((size_t)L_VERTS*4);
  unsigned char* mstF=(unsigned char*)alloc((size_t)N_EDGES);
  u32* blockCnt =(u32*)alloc(256*4);
  u32* blockBase=(u32*)alloc(256*4);
  u32* mepair   =(u32*)alloc((size_t)PADM*4);    // compacted (dst<<16)|src, tail padded 0
  u32* bctr     =(u32*)alloc(512);               // per-round hooked flags
  size_t endA=off;
  // phase B (poly softarea) — overlays phase A scratch
  off=scratch0;
  u32* ccChsum  =(u32*)alloc((size_t)L_VERTS*4);     // childCnt for prep_init
  u32* J0       =(u32*)alloc((size_t)N_NODES*4);
  u32* J1       =(u32*)alloc((size_t)N_NODES*4);
  uint2* A0     =(uint2*)alloc((size_t)N_NODES*8);
  uint2* A1     =(uint2*)alloc((size_t)N_NODES*8);   // survives: accF after 6 launches
  float* nodeM  =(float*)alloc((size_t)6*NODEPAD*4);
  size_t endB=off;
  float* leafM  =(float*)ccChsum;

  if((endA>ws_size)||(endB>ws_size)){
    ws_too_small<<<(N_NODES+255)/256,256,0,stream>>>(out);
    return;
  }

  u16* lid16    =(u16*)vals1;
  u32* epair    =keys0;                          // keys dead after sort
  u16* outChA16 =(u16*)histG;
  u16* outChB16 =(u16*)keys0;                    // written by p2 (after Borůvka done with epair)
  u16* compR16  =svsize16;
  u16* compTop16=svnext16;
  u32* szG      =(u32*)usize16;                  // u32[L_VERTS] aliases usize16; dead after p1

  // --- sort (+ fused tree-array init) ---
  init_keys<<<(N_NODES+255)/256,256,0,stream>>>(w,keys0,vals0,szG,canonTop16,parent,alt);
  for(int pass=0;pass<4;pass++){
    const u32* iv = (pass&1)?vals1:vals0;
    u32* ov = (pass&1)?vals0:vals1;
    int shift=pass*8;
    radix_hist   <<<NB,TPB,0,stream>>>(iv,keys0,histG,shift);
    radix_scan   <<<1,1024,0,stream>>>(histG);
    radix_scatter<<<NB,TPB,0,stream>>>(iv,keys0,ov,histG,shift);
  }
  build_epair<<<(N_EDGES+255)/256,256,0,stream>>>(vals0,src,dst,epair);
  // --- Borůvka MST filter on sorted ranks (unique keys == stable Kruskal) ---
  bor_init<<<CBK,CT,0,stream>>>(parentB,minEa,minEb,mstF,bctr);
  for(int r=0;r<16;r++){   // dead rounds early-return via stream-ordered flag
    u32* mcur=(r&1)?minEb:minEa;
    u32* mnxt=(r&1)?minEa:minEb;
    bor_minedge <<<CBK,CT,0,stream>>>(epair,parentB,mcur,mstF,bctr,r);
    bor_hookA   <<<L_VERTS/CT,CT,0,stream>>>(epair,parentB,mcur,nextB,mstF,bctr,r);
    bor_hookB   <<<L_VERTS/CT,CT,0,stream>>>(parentB,mcur,mnxt,nextB,bctr,r);
  }
  mst_count  <<<CBK,CT,0,stream>>>(mstF,blockCnt);
  mst_scan   <<<1,256,0,stream>>>(blockCnt,blockBase,mepair);
  mst_scatter<<<CBK,CT,0,stream>>>(mstF,blockBase,vals0,epair,w,mepair,alt);
  // --- tree build on 65535-edge compacted stream (86 chunks) ---
  p1_checkpoints<<<1,1024,0,stream>>>(mepair,szG,lid16,svroot16,svsize16,svnext16,mG);
  p2_chunk<<<CCHM,64,0,stream>>>(lid16,svsize16,svnext16,mG,outChA16,outChB16,
                                 parent,usize16,compR16,compTop16,ncomp);
  p3_stitch<<<1,1024,0,stream>>>(outChA16,outChB16,svroot16,
                                 compR16,compTop16,ncomp,canonTop16,parent);
  // --- DFS coordinates via fused pointer doubling (6 launches x 3 rounds) ---
  zero_cc<<<(L_VERTS+255)/256,256,0,stream>>>(ccChsum,ctr);
  prep_init<<<(NODEPAD+255)/256,256,0,stream>>>(parent,usize16,ccChsum,J1,A1,out,nodeM);
  for(int r=0;r<6;r++){
    if((r&1)==0) triple_round<<<(N_NODES+255)/256,256,0,stream>>>(J1,A1,J0,A0);
    else         triple_round<<<(N_NODES+255)/256,256,0,stream>>>(J0,A0,J1,A1);
  }
  const uint2* accF=A1;
  // --- single merged moment batch (all 6 h-rows) ---
  scatter_all<<<(N_NODES+255)/256,256,0,stream>>>(parent,alt,usize16,accF,leafM,nodeM);
  scanAll<<<1152,256,0,stream>>>(leafM,nodeM,bsumL,bsumN,ctr);
  eval_all<<<(N_NODES+255)/256,256,0,stream>>>(accF,alt,usize16,leafM,nodeM,bsumL,bsumN,out);
}